// Round 9
// baseline (94.685 us; speedup 1.0000x reference)
//
#include <hip/hip_runtime.h>
#include <math.h>

#define V_ 2
#define C_ 128
#define H_ 64
#define W_ 128
#define D_ 32
#define HW_ (H_*W_)
#define PIXELS (V_*HW_)

#define PI_F 3.14159265358979323846f
#define TWO_PI_F 6.28318530717958647692f

typedef _Float16 half2_t __attribute__((ext_vector_type(2)));
typedef _Float16 half8_t __attribute__((ext_vector_type(8)));

// workspace: T = f16 features, layout (V,H,W,C), 4 MB

__device__ __forceinline__ float fdot2f(half2_t a, half2_t b, float c) {
#if __has_builtin(__builtin_amdgcn_fdot2)
  return __builtin_amdgcn_fdot2(a, b, c, false);
#else
  return (float)a[0] * (float)b[0] + ((float)a[1] * (float)b[1] + c);
#endif
}

// ---------------- transpose (V,C,H,W) fp32 -> (V,H,W,C) f16 ----------------
__global__ __launch_bounds__(256) void transpose_kernel(const float* __restrict__ f,
                                                        _Float16* __restrict__ T) {
  __shared__ float tile[64][W_ + 2];
  const int b = blockIdx.x;
  const int chalf = b & 1;
  const int h = (b >> 1) & (H_ - 1);
  const int v = b >> 7;
  const int c0 = chalf * 64;
  const int t = threadIdx.x;

  const float* src = f + (((size_t)(v * C_ + c0)) * H_ + h) * W_;
  {
    const int w2 = t & 63;
    const int cb = t >> 6;
#pragma unroll
    for (int p = 0; p < 16; ++p) {
      const int c = cb + p * 4;
      const float2 x = *(const float2*)(src + (size_t)c * HW_ + w2 * 2);
      tile[c][w2 * 2]     = x.x;
      tile[c][w2 * 2 + 1] = x.y;
    }
  }
  __syncthreads();
  _Float16* dst = T + (((size_t)v * H_ + h) * W_) * C_ + c0;
  {
    const int w = t & 127;        // pixel column
    const int oh = t >> 7;        // oct half selector
#pragma unroll
    for (int p = 0; p < 4; ++p) {
      const int oct = oh + p * 2;
      half8_t o;
#pragma unroll
      for (int k = 0; k < 8; ++k)
        o[k] = (_Float16)tile[oct * 8 + k][w];
      *(half8_t*)(dst + (size_t)w * C_ + oct * 8) = o;
    }
  }
}

__device__ __forceinline__ float bperm_f(int byte_idx, float x) {
  return __int_as_float(__builtin_amdgcn_ds_bpermute(byte_idx, __float_as_int(x)));
}

// ---------------- main correlation kernel ----------------
// one 64-lane wave per output pixel. lane = (corner c=lane>>4 [bit4=x,bit5=y],
// channel-oct cl=lane&15). Per depth: ONE dwordx4 wave-load covers all 4
// bilinear corners. DEDUP: consecutive depths sampling the identical pixel
// quad (ballot-detected, wave-uniform SGPR mask) skip both the load and the
// dot2s -- attacks the per-CU divergent-load address-throughput floor.
__global__ __launch_bounds__(256, 4) void corr_kernel(const _Float16* __restrict__ T,
                                                      const float* __restrict__ ex,
                                                      const float* __restrict__ nearp,
                                                      const float* __restrict__ farp,
                                                      float* __restrict__ out) {
  const int lane = threadIdx.x & 63;
  const int pix  = blockIdx.x * 4 + (threadIdx.x >> 6);
  const int n   = pix >> 13;
  const int rem = pix & 8191;
  const int h   = rem >> 7;
  const int w   = rem & 127;
  const int cl  = lane & 15;          // channel oct
  const unsigned mx = ((lane >> 4) & 1) ? 0xFFFFFFFFu : 0u;  // x1 column lanes
  const unsigned my = (lane >= 32)     ? 0xFFFFFFFFu : 0u;   // y1 row lanes

  const char* F0b = (const char*)(T + (size_t)n       * HW_ * C_);
  const char* F1b = (const char*)(T + (size_t)(1 - n) * HW_ * C_);

  const half8_t f0v = *(const half8_t*)(F0b + ((size_t)(h * W_ + w)) * 256 + cl * 16);
  const half2_t f0a = __builtin_shufflevector(f0v, f0v, 0, 1);
  const half2_t f0b_ = __builtin_shufflevector(f0v, f0v, 2, 3);
  const half2_t f0c = __builtin_shufflevector(f0v, f0v, 4, 5);
  const half2_t f0d = __builtin_shufflevector(f0v, f0v, 6, 7);

  // ---- pose (wave-uniform) ----
  float PR[9], PT[3];
  {
    float R0[9], R1[9];
#pragma unroll
    for (int r = 0; r < 3; ++r)
#pragma unroll
      for (int c = 0; c < 3; ++c) {
        R0[r * 3 + c] = ex[r * 4 + c];
        R1[r * 3 + c] = ex[16 + r * 4 + c];
      }
    const float d0 = ex[3]  - ex[19];
    const float d1 = ex[7]  - ex[23];
    const float d2 = ex[11] - ex[27];
#pragma unroll
    for (int i = 0; i < 3; ++i) {
#pragma unroll
      for (int c = 0; c < 3; ++c)
        PR[i * 3 + c] = R1[i] * R0[c] + R1[3 + i] * R0[3 + c] + R1[6 + i] * R0[6 + c];
      PT[i] = R1[i] * d0 + R1[3 + i] * d1 + R1[6 + i] * d2;
    }
  }
  float Rm[9], tv[3];
  if (n == 0) {
#pragma unroll
    for (int i = 0; i < 9; ++i) Rm[i] = PR[i];
#pragma unroll
    for (int i = 0; i < 3; ++i) tv[i] = PT[i];
  } else {
#pragma unroll
    for (int r = 0; r < 3; ++r)
#pragma unroll
      for (int c = 0; c < 3; ++c) Rm[r * 3 + c] = PR[c * 3 + r];
#pragma unroll
    for (int r = 0; r < 3; ++r)
      tv[r] = -(PR[r] * PT[0] + PR[3 + r] * PT[1] + PR[6 + r] * PT[2]);
  }

  // ---- ray direction (wave-uniform) ----
  const float theta = ((float)w + 0.5f) * (TWO_PI_F / (float)W_);
  const float phi   = ((float)h + 0.5f) * (PI_F / (float)H_);
  const float sphi = sinf(phi);
  const float dx_ = sphi * sinf(theta);
  const float dy_ = cosf(phi);
  const float dz_ = sphi * cosf(theta);
  const float rdx = Rm[0] * dx_ + Rm[1] * dy_ + Rm[2] * dz_;
  const float rdy = Rm[3] * dx_ + Rm[4] * dy_ + Rm[5] * dz_;
  const float rdz = Rm[6] * dx_ + Rm[7] * dy_ + Rm[8] * dz_;

  // ---- per-lane warp for depth dl = lane&31 ----
  const int dl = lane & 31;
  const float mind = 1.f / farp[n];
  const float maxd = 1.f / nearp[n];
  const float depth = 1.f / (mind + ((float)dl / 31.f) * (maxd - mind));
  const float px = depth * rdx + tv[0];
  const float py = depth * rdy + tv[1];
  const float pz = depth * rdz + tv[2];
  float r = sqrtf(px * px + py * py + pz * pz);
  r = fmaxf(r, 0.001f);
  const float cy = fminf(fmaxf(py / r, -1.f), 1.f);
  const float phiw = acosf(cy);
  float thw = atan2f(px, pz);
  if (thw < 0.f) thw += TWO_PI_F;
  const float ix = thw * ((float)(W_ - 1) / TWO_PI_F);
  const float iy = phiw * ((float)(H_ - 1) / PI_F);

  const float x0f = floorf(ix), y0f = floorf(iy);
  const float x1f = x0f + 1.f,  y1f = y0f + 1.f;
  const float wx1 = ix - x0f, wx0 = 1.f - wx1;
  const float wy1 = iy - y0f, wy0 = 1.f - wy1;
  const float vx0 = (x0f >= 0.f && x0f <= (float)(W_ - 1)) ? 1.f : 0.f;
  const float vx1 = (x1f >= 0.f && x1f <= (float)(W_ - 1)) ? 1.f : 0.f;
  const float vy0 = (y0f >= 0.f && y0f <= (float)(H_ - 1)) ? 1.f : 0.f;
  const float vy1 = (y1f >= 0.f && y1f <= (float)(H_ - 1)) ? 1.f : 0.f;
  const int xi0 = (int)fminf(fmaxf(x0f, 0.f), (float)(W_ - 1));
  const int xi1 = (int)fminf(fmaxf(x1f, 0.f), (float)(W_ - 1));
  const int yi0 = (int)fminf(fmaxf(y0f, 0.f), (float)(H_ - 1));
  const int yi1 = (int)fminf(fmaxf(y1f, 0.f), (float)(H_ - 1));
  const float w00 = wx0 * wy0 * vx0 * vy0;
  const float w10 = wx1 * wy0 * vx1 * vy0;
  const float w01 = wx0 * wy1 * vx0 * vy1;
  const float w11 = wx1 * wy1 * vx1 * vy1;
  // lane l holds weights for depth l&31, x-column l>>5:
  const float wA_pre = (lane >= 32) ? w10 : w00;   // row y0
  const float wB_pre = (lane >= 32) ? w11 : w01;   // row y1
  // pack: bits 8..20 = (yi0*W+xi0)*256 (byte idx, f16), bit30 = xstep, bit31 = ystep
  const unsigned packed = (unsigned)((yi0 * W_ + xi0) * 256)
                        | ((unsigned)(xi1 - xi0) << 30)
                        | ((unsigned)(yi1 - yi0) << 31);

  // dedup mask: bit d set => depth d samples the identical pixel quad as d-1
  // (packed depends only on dl, so lanes 1..31 carry depths 1..31)
  const int pk_prev = __shfl((int)packed, (lane - 1) & 63, 64);
  const unsigned long long bl = __ballot(dl > 0 && (int)packed == pk_prev);
  const unsigned dupm = (unsigned)bl;   // low 32 bits = depths 0..31

  const unsigned laneoff = (unsigned)(cl * 16);

#define LOAD_DEPTH(d) ({                                                     \
    const unsigned pk  = (unsigned)__builtin_amdgcn_readlane((int)packed, (d)); \
    const unsigned sdx = (pk >> 22) & 256u;                                  \
    const unsigned sdy = ((unsigned)((int)pk >> 31)) & 32768u;               \
    const char* sbase = F1b + (pk & 0x3FFFFFu);                              \
    const unsigned voff = (mx & sdx) + (my & sdy) + laneoff;                 \
    *(const half8_t*)(sbase + voff); })

#define DOT(s) ({                                                            \
    float dt_ = fdot2f(__builtin_shufflevector((s), (s), 0, 1), f0a, 0.f);   \
    dt_ = fdot2f(__builtin_shufflevector((s), (s), 2, 3), f0b_, dt_);        \
    dt_ = fdot2f(__builtin_shufflevector((s), (s), 4, 5), f0c, dt_);         \
    fdot2f(__builtin_shufflevector((s), (s), 6, 7), f0d, dt_); })

  float acc[32];
  {
    float dlast = 0.f;
#pragma unroll
    for (int d = 0; d < 32; ++d) {
      if (!((dupm >> d) & 1u)) {         // wave-uniform branch (SGPR mask)
        const half8_t s = LOAD_DEPTH(d);
        dlast = DOT(s);
      }
      acc[d] = dlast;
    }
  }
#undef LOAD_DEPTH
#undef DOT

  // ---- butterfly: fold channel bits first (xor 1,2,4,8) ----
  float a16[16];
#pragma unroll
  for (int j = 0; j < 16; ++j) {
    const bool hi = (lane & 1) != 0;
    const float keep = hi ? acc[j + 16] : acc[j];
    const float send = hi ? acc[j] : acc[j + 16];
    a16[j] = keep + __shfl_xor(send, 1, 64);
  }
  float a8[8];
#pragma unroll
  for (int j = 0; j < 8; ++j) {
    const bool hi = (lane & 2) != 0;
    const float keep = hi ? a16[j + 8] : a16[j];
    const float send = hi ? a16[j] : a16[j + 8];
    a8[j] = keep + __shfl_xor(send, 2, 64);
  }
  float a4[4];
#pragma unroll
  for (int j = 0; j < 4; ++j) {
    const bool hi = (lane & 4) != 0;
    const float keep = hi ? a8[j + 4] : a8[j];
    const float send = hi ? a8[j] : a8[j + 4];
    a4[j] = keep + __shfl_xor(send, 4, 64);
  }
  float a2[2];
#pragma unroll
  for (int j = 0; j < 2; ++j) {
    const bool hi = (lane & 8) != 0;
    const float keep = hi ? a4[j + 2] : a4[j];
    const float send = hi ? a4[j] : a4[j + 2];
    a2[j] = keep + __shfl_xor(send, 8, 64);
  }

  // lane bits {0,1,2,3} = depth bits {4,3,2,1}; array idx = depth bit 0;
  // lane bit4 = x-corner, bit5 = y-row. Apply weights via bpermute.
  {
    const int dbase = ((lane & 1) << 4) | (((lane >> 1) & 1) << 3)
                    | (((lane >> 2) & 1) << 2) | (((lane >> 3) & 1) << 1);
    const int xsel = (lane >> 4) & 1;
    const bool rowy1 = (lane & 32) != 0;
#pragma unroll
    for (int i = 0; i < 2; ++i) {
      const int idx = (xsel * 32 + dbase + i) * 4;
      const float wa = bperm_f(idx, wA_pre);
      const float wb = bperm_f(idx, wB_pre);
      a2[i] *= rowy1 ? wb : wa;
    }
  }

  // fold x-corner (xor16), then y-row (xor32)
  float v1;
  {
    const bool hi = (lane & 16) != 0;
    const float keep = hi ? a2[1] : a2[0];
    const float send = hi ? a2[0] : a2[1];
    v1 = keep + __shfl_xor(send, 16, 64);
  }
  v1 += __shfl_xor(v1, 32, 64);

  if (lane < 32) {
    const int d = ((lane & 1) << 4) | (((lane >> 1) & 1) << 3)
                | (((lane >> 2) & 1) << 2) | (((lane >> 3) & 1) << 1)
                | ((lane >> 4) & 1);
    out[(((size_t)n * D_ + d) * H_ + h) * W_ + w] = v1 * 0.08838834764831845f; // 1/sqrt(128)
  }
}

extern "C" void kernel_launch(void* const* d_in, const int* in_sizes, int n_in,
                              void* d_out, int out_size, void* d_ws, size_t ws_size,
                              hipStream_t stream) {
  const float* features = (const float*)d_in[0];
  const float* extr     = (const float*)d_in[1];
  const float* nearp    = (const float*)d_in[2];
  const float* farp     = (const float*)d_in[3];
  float* out = (float*)d_out;
  _Float16* T = (_Float16*)d_ws;

  hipLaunchKernelGGL(transpose_kernel, dim3(V_ * H_ * 2), dim3(256), 0, stream, features, T);
  hipLaunchKernelGGL(corr_kernel, dim3(PIXELS / 4), dim3(256), 0, stream,
                     T, extr, nearp, farp, out);
}

// Round 10
// 90.118 us; speedup vs baseline: 1.0507x; 1.0507x over previous
//
#include <hip/hip_runtime.h>
#include <math.h>

#define V_ 2
#define C_ 128
#define H_ 64
#define W_ 128
#define D_ 32
#define HW_ (H_*W_)
#define PIXELS (V_*HW_)

#define PI_F 3.14159265358979323846f
#define TWO_PI_F 6.28318530717958647692f

typedef _Float16 half2_t __attribute__((ext_vector_type(2)));
typedef _Float16 half8_t __attribute__((ext_vector_type(8)));

// workspace: T = f16 features, layout (V,H,W,C), 4 MB

__device__ __forceinline__ float fdot2f(half2_t a, half2_t b, float c) {
#if __has_builtin(__builtin_amdgcn_fdot2)
  return __builtin_amdgcn_fdot2(a, b, c, false);
#else
  return (float)a[0] * (float)b[0] + ((float)a[1] * (float)b[1] + c);
#endif
}

// ---------------- transpose (V,C,H,W) fp32 -> (V,H,W,C) f16 ----------------
__global__ __launch_bounds__(256) void transpose_kernel(const float* __restrict__ f,
                                                        _Float16* __restrict__ T) {
  __shared__ float tile[64][W_ + 2];
  const int b = blockIdx.x;
  const int chalf = b & 1;
  const int h = (b >> 1) & (H_ - 1);
  const int v = b >> 7;
  const int c0 = chalf * 64;
  const int t = threadIdx.x;

  const float* src = f + (((size_t)(v * C_ + c0)) * H_ + h) * W_;
  {
    const int w2 = t & 63;
    const int cb = t >> 6;
#pragma unroll
    for (int p = 0; p < 16; ++p) {
      const int c = cb + p * 4;
      const float2 x = *(const float2*)(src + (size_t)c * HW_ + w2 * 2);
      tile[c][w2 * 2]     = x.x;
      tile[c][w2 * 2 + 1] = x.y;
    }
  }
  __syncthreads();
  _Float16* dst = T + (((size_t)v * H_ + h) * W_) * C_ + c0;
  {
    const int w = t & 127;        // pixel column
    const int oh = t >> 7;        // oct half selector
#pragma unroll
    for (int p = 0; p < 4; ++p) {
      const int oct = oh + p * 2;
      half8_t o;
#pragma unroll
      for (int k = 0; k < 8; ++k)
        o[k] = (_Float16)tile[oct * 8 + k][w];
      *(half8_t*)(dst + (size_t)w * C_ + oct * 8) = o;
    }
  }
}

__device__ __forceinline__ float bperm_f(int byte_idx, float x) {
  return __int_as_float(__builtin_amdgcn_ds_bpermute(byte_idx, __float_as_int(x)));
}

// depth processing order: {0..7, 16..23, 8..15, 24..31} so butterfly stage-1
// pairs (j, j+16) can fold as soon as both halves exist (caps acc pressure).
#define ORD(i) ((((i) >> 3 & 1) << 4) | (((i) >> 4) << 3) | ((i) & 7))

// ---------------- main correlation kernel ----------------
// BLOCK = 1024 threads = 16 waves = 16 consecutive pixels (same h row).
// lane = (corner c=lane>>4 [bit4=x,bit5=y], channel-oct cl=lane&15).
// Per depth: ONE dwordx4 wave-load covers all 4 bilinear corners (f16 pixel
// vec = 256B; x-pair contiguous 512B; y-row via per-lane offset).
// 16-deep circular prefetch; weights applied after the channel butterfly.
// NOTE (R9 post-mortem): dedup of consecutive identical quads REGRESSES —
// inverse-depth sampling concentrates candidates at near depths (high
// parallax, few duplicates) and the mask branch serializes the loop.
__global__ __launch_bounds__(1024, 4) void corr_kernel(const _Float16* __restrict__ T,
                                                       const float* __restrict__ ex,
                                                       const float* __restrict__ nearp,
                                                       const float* __restrict__ farp,
                                                       float* __restrict__ out) {
  const int lane = threadIdx.x & 63;
  const int pix  = blockIdx.x * 16 + (threadIdx.x >> 6);
  const int n   = pix >> 13;
  const int rem = pix & 8191;
  const int h   = rem >> 7;
  const int w   = rem & 127;
  const int cl  = lane & 15;          // channel oct
  const unsigned mx = ((lane >> 4) & 1) ? 0xFFFFFFFFu : 0u;  // x1 column lanes
  const unsigned my = (lane >= 32)     ? 0xFFFFFFFFu : 0u;   // y1 row lanes

  const char* F0b = (const char*)(T + (size_t)n       * HW_ * C_);
  const char* F1b = (const char*)(T + (size_t)(1 - n) * HW_ * C_);

  const half8_t f0v = *(const half8_t*)(F0b + ((size_t)(h * W_ + w)) * 256 + cl * 16);
  const half2_t f0a = __builtin_shufflevector(f0v, f0v, 0, 1);
  const half2_t f0b_ = __builtin_shufflevector(f0v, f0v, 2, 3);
  const half2_t f0c = __builtin_shufflevector(f0v, f0v, 4, 5);
  const half2_t f0d = __builtin_shufflevector(f0v, f0v, 6, 7);

  // ---- pose (wave-uniform) ----
  float PR[9], PT[3];
  {
    float R0[9], R1[9];
#pragma unroll
    for (int r = 0; r < 3; ++r)
#pragma unroll
      for (int c = 0; c < 3; ++c) {
        R0[r * 3 + c] = ex[r * 4 + c];
        R1[r * 3 + c] = ex[16 + r * 4 + c];
      }
    const float d0 = ex[3]  - ex[19];
    const float d1 = ex[7]  - ex[23];
    const float d2 = ex[11] - ex[27];
#pragma unroll
    for (int i = 0; i < 3; ++i) {
#pragma unroll
      for (int c = 0; c < 3; ++c)
        PR[i * 3 + c] = R1[i] * R0[c] + R1[3 + i] * R0[3 + c] + R1[6 + i] * R0[6 + c];
      PT[i] = R1[i] * d0 + R1[3 + i] * d1 + R1[6 + i] * d2;
    }
  }
  float Rm[9], tv[3];
  if (n == 0) {
#pragma unroll
    for (int i = 0; i < 9; ++i) Rm[i] = PR[i];
#pragma unroll
    for (int i = 0; i < 3; ++i) tv[i] = PT[i];
  } else {
#pragma unroll
    for (int r = 0; r < 3; ++r)
#pragma unroll
      for (int c = 0; c < 3; ++c) Rm[r * 3 + c] = PR[c * 3 + r];
#pragma unroll
    for (int r = 0; r < 3; ++r)
      tv[r] = -(PR[r] * PT[0] + PR[3 + r] * PT[1] + PR[6 + r] * PT[2]);
  }

  // ---- ray direction (wave-uniform) ----
  const float theta = ((float)w + 0.5f) * (TWO_PI_F / (float)W_);
  const float phi   = ((float)h + 0.5f) * (PI_F / (float)H_);
  const float sphi = sinf(phi);
  const float dx_ = sphi * sinf(theta);
  const float dy_ = cosf(phi);
  const float dz_ = sphi * cosf(theta);
  const float rdx = Rm[0] * dx_ + Rm[1] * dy_ + Rm[2] * dz_;
  const float rdy = Rm[3] * dx_ + Rm[4] * dy_ + Rm[5] * dz_;
  const float rdz = Rm[6] * dx_ + Rm[7] * dy_ + Rm[8] * dz_;

  // ---- per-lane warp for depth dl = lane&31 ----
  const int dl = lane & 31;
  const float mind = 1.f / farp[n];
  const float maxd = 1.f / nearp[n];
  const float depth = 1.f / (mind + ((float)dl / 31.f) * (maxd - mind));
  const float px = depth * rdx + tv[0];
  const float py = depth * rdy + tv[1];
  const float pz = depth * rdz + tv[2];
  float r = sqrtf(px * px + py * py + pz * pz);
  r = fmaxf(r, 0.001f);
  const float cy = fminf(fmaxf(py / r, -1.f), 1.f);
  const float phiw = acosf(cy);
  float thw = atan2f(px, pz);
  if (thw < 0.f) thw += TWO_PI_F;
  const float ix = thw * ((float)(W_ - 1) / TWO_PI_F);
  const float iy = phiw * ((float)(H_ - 1) / PI_F);

  const float x0f = floorf(ix), y0f = floorf(iy);
  const float x1f = x0f + 1.f,  y1f = y0f + 1.f;
  const float wx1 = ix - x0f, wx0 = 1.f - wx1;
  const float wy1 = iy - y0f, wy0 = 1.f - wy1;
  const float vx0 = (x0f >= 0.f && x0f <= (float)(W_ - 1)) ? 1.f : 0.f;
  const float vx1 = (x1f >= 0.f && x1f <= (float)(W_ - 1)) ? 1.f : 0.f;
  const float vy0 = (y0f >= 0.f && y0f <= (float)(H_ - 1)) ? 1.f : 0.f;
  const float vy1 = (y1f >= 0.f && y1f <= (float)(H_ - 1)) ? 1.f : 0.f;
  const int xi0 = (int)fminf(fmaxf(x0f, 0.f), (float)(W_ - 1));
  const int xi1 = (int)fminf(fmaxf(x1f, 0.f), (float)(W_ - 1));
  const int yi0 = (int)fminf(fmaxf(y0f, 0.f), (float)(H_ - 1));
  const int yi1 = (int)fminf(fmaxf(y1f, 0.f), (float)(H_ - 1));
  const float w00 = wx0 * wy0 * vx0 * vy0;
  const float w10 = wx1 * wy0 * vx1 * vy0;
  const float w01 = wx0 * wy1 * vx0 * vy1;
  const float w11 = wx1 * wy1 * vx1 * vy1;
  // lane l holds weights for depth l&31, x-column l>>5:
  const float wA_pre = (lane >= 32) ? w10 : w00;   // row y0
  const float wB_pre = (lane >= 32) ? w11 : w01;   // row y1
  // pack: bits 8..20 = (yi0*W+xi0)*256 (byte idx, f16), bit30 = xstep, bit31 = ystep
  const unsigned packed = (unsigned)((yi0 * W_ + xi0) * 256)
                        | ((unsigned)(xi1 - xi0) << 30)
                        | ((unsigned)(yi1 - yi0) << 31);

  const unsigned laneoff = (unsigned)(cl * 16);

#define LOAD_DEPTH(d) ({                                                     \
    const unsigned pk  = (unsigned)__builtin_amdgcn_readlane((int)packed, (d)); \
    const unsigned sdx = (pk >> 22) & 256u;                                  \
    const unsigned sdy = ((unsigned)((int)pk >> 31)) & 32768u;               \
    const char* sbase = F1b + (pk & 0x3FFFFFu);                              \
    const unsigned voff = (mx & sdx) + (my & sdy) + laneoff;                 \
    *(const half8_t*)(sbase + voff); })

#define DOT(s) ({                                                            \
    float dt_ = fdot2f(__builtin_shufflevector((s), (s), 0, 1), f0a, 0.f);   \
    dt_ = fdot2f(__builtin_shufflevector((s), (s), 2, 3), f0b_, dt_);        \
    dt_ = fdot2f(__builtin_shufflevector((s), (s), 4, 5), f0c, dt_);         \
    fdot2f(__builtin_shufflevector((s), (s), 6, 7), f0d, dt_); })

  // 16-deep circular prefetch; process order ORD: {0..7,16..23,8..15,24..31}
  half8_t cbuf[16];
#pragma unroll
  for (int i = 0; i < 16; ++i) cbuf[i] = LOAD_DEPTH(ORD(i));

  float a16[16];
  const bool hi1 = (lane & 1) != 0;
  {
    float accA[8], accB[8];
    // consume depths 0..7 (slots 0..7), reissue slots for depths 8..15
#pragma unroll
    for (int i = 0; i < 8; ++i) {
      accA[i] = DOT(cbuf[i]);
      cbuf[i] = LOAD_DEPTH(ORD(16 + i));
    }
    // consume depths 16..23 (slots 8..15), reissue for depths 24..31
#pragma unroll
    for (int i = 0; i < 8; ++i) {
      accB[i] = DOT(cbuf[8 + i]);
      cbuf[8 + i] = LOAD_DEPTH(ORD(24 + i));
    }
    // fold stage xor1, pairs (idx j, idx j+16), j = 0..7
#pragma unroll
    for (int j = 0; j < 8; ++j) {
      const float keep = hi1 ? accB[j] : accA[j];
      const float send = hi1 ? accA[j] : accB[j];
      a16[j] = keep + __shfl_xor(send, 1, 64);
    }
    // consume depths 8..15 (slots 0..7) and 24..31 (slots 8..15)
#pragma unroll
    for (int i = 0; i < 8; ++i) accA[i] = DOT(cbuf[i]);
#pragma unroll
    for (int i = 0; i < 8; ++i) accB[i] = DOT(cbuf[8 + i]);
    // fold stage xor1, pairs (idx 8+j, idx 24+j)
#pragma unroll
    for (int j = 0; j < 8; ++j) {
      const float keep = hi1 ? accB[j] : accA[j];
      const float send = hi1 ? accA[j] : accB[j];
      a16[8 + j] = keep + __shfl_xor(send, 1, 64);
    }
  }
#undef LOAD_DEPTH
#undef DOT

  // ---- remaining butterfly stages (xor 2, 4, 8) ----
  float a8[8];
#pragma unroll
  for (int j = 0; j < 8; ++j) {
    const bool hi = (lane & 2) != 0;
    const float keep = hi ? a16[j + 8] : a16[j];
    const float send = hi ? a16[j] : a16[j + 8];
    a8[j] = keep + __shfl_xor(send, 2, 64);
  }
  float a4[4];
#pragma unroll
  for (int j = 0; j < 4; ++j) {
    const bool hi = (lane & 4) != 0;
    const float keep = hi ? a8[j + 4] : a8[j];
    const float send = hi ? a8[j] : a8[j + 4];
    a4[j] = keep + __shfl_xor(send, 4, 64);
  }
  float a2[2];
#pragma unroll
  for (int j = 0; j < 2; ++j) {
    const bool hi = (lane & 8) != 0;
    const float keep = hi ? a4[j + 2] : a4[j];
    const float send = hi ? a4[j] : a4[j + 2];
    a2[j] = keep + __shfl_xor(send, 8, 64);
  }

  // lane bits {0,1,2,3} = depth bits {4,3,2,1}; array idx = depth bit 0;
  // lane bit4 = x-corner, bit5 = y-row. Apply weights via bpermute.
  {
    const int dbase = ((lane & 1) << 4) | (((lane >> 1) & 1) << 3)
                    | (((lane >> 2) & 1) << 2) | (((lane >> 3) & 1) << 1);
    const int xsel = (lane >> 4) & 1;
    const bool rowy1 = (lane & 32) != 0;
#pragma unroll
    for (int i = 0; i < 2; ++i) {
      const int idx = (xsel * 32 + dbase + i) * 4;
      const float wa = bperm_f(idx, wA_pre);
      const float wb = bperm_f(idx, wB_pre);
      a2[i] *= rowy1 ? wb : wa;
    }
  }

  // fold x-corner (xor16), then y-row (xor32)
  float v1;
  {
    const bool hi = (lane & 16) != 0;
    const float keep = hi ? a2[1] : a2[0];
    const float send = hi ? a2[0] : a2[1];
    v1 = keep + __shfl_xor(send, 16, 64);
  }
  v1 += __shfl_xor(v1, 32, 64);

  if (lane < 32) {
    const int d = ((lane & 1) << 4) | (((lane >> 1) & 1) << 3)
                | (((lane >> 2) & 1) << 2) | (((lane >> 3) & 1) << 1)
                | ((lane >> 4) & 1);
    out[(((size_t)n * D_ + d) * H_ + h) * W_ + w] = v1 * 0.08838834764831845f; // 1/sqrt(128)
  }
}

extern "C" void kernel_launch(void* const* d_in, const int* in_sizes, int n_in,
                              void* d_out, int out_size, void* d_ws, size_t ws_size,
                              hipStream_t stream) {
  const float* features = (const float*)d_in[0];
  const float* extr     = (const float*)d_in[1];
  const float* nearp    = (const float*)d_in[2];
  const float* farp     = (const float*)d_in[3];
  float* out = (float*)d_out;
  _Float16* T = (_Float16*)d_ws;

  hipLaunchKernelGGL(transpose_kernel, dim3(V_ * H_ * 2), dim3(256), 0, stream, features, T);
  hipLaunchKernelGGL(corr_kernel, dim3(PIXELS / 16), dim3(1024), 0, stream,
                     T, extr, nearp, farp, out);
}